// Round 2
// baseline (1425.502 us; speedup 1.0000x reference)
//
#include <hip/hip_runtime.h>
#include <hip/hip_bf16.h>

#define N_NODES 200000
#define E1 1600000
#define N1P 100000
#define E2P 100000
#define N2P 50000
#define BGR 1000
#define C1 32
#define C2 64
#define HIDN 25
#define NCLS 10

typedef short short8 __attribute__((ext_vector_type(8)));
typedef int int4v __attribute__((ext_vector_type(4)));
typedef float f32x4 __attribute__((ext_vector_type(4)));
typedef float f32x2 __attribute__((ext_vector_type(2)));

union FragU { int4v i; short8 s; };

__device__ __forceinline__ float elu1(float v) {
    return v > 0.f ? v : expm1f(v);
}
__device__ __forceinline__ float bf2f(unsigned short u) {
    return __uint_as_float(((unsigned int)u) << 16);
}
__device__ __forceinline__ unsigned int pk_bf16(float a, float b) {
    unsigned int r;
    asm("v_cvt_pk_bf16_f32 %0, %1, %2" : "=v"(r) : "v"(a), "v"(b));
    return r;
}

// ---------------- conv1: thread per edge; msg[32] fp32; 16 packed bf16 atomics
__global__ __launch_bounds__(256) void conv1_kernel(
    const float* __restrict__ x, const float* __restrict__ ea,
    const int* __restrict__ ei,
    const float* __restrict__ w1, const float* __restrict__ b1,
    const float* __restrict__ w2, const float* __restrict__ b2,
    unsigned short* __restrict__ agg1b)
{
    int e = blockIdx.x * 256 + threadIdx.x;
    if (e >= E1) return;
    f32x2 a = ((const f32x2*)ea)[e];
    int s = ei[e], d = ei[E1 + e];
    float xv = x[s];

    float hid[HIDN];
#pragma unroll
    for (int h = 0; h < HIDN; ++h) {
        float v = fmaf(a.x, w1[h], fmaf(a.y, w1[HIDN + h], b1[h]));
        hid[h] = fmaxf(v, 0.f);
    }
    float msg[C1];
#pragma unroll
    for (int o = 0; o < C1; ++o) msg[o] = b2[o];
#pragma unroll 1
    for (int h = 0; h < HIDN; ++h) {
        float hv = hid[h];
#pragma unroll
        for (int o = 0; o < C1; ++o)
            msg[o] = fmaf(hv, w2[h * C1 + o], msg[o]);
    }
    unsigned short* base = agg1b + (size_t)d * C1;
#pragma unroll
    for (int k = 0; k < 16; ++k) {
        unsigned int pk = pk_bf16(msg[2 * k] * xv, msg[2 * k + 1] * xv);
        asm volatile("global_atomic_pk_add_bf16 %0, %1, off"
                     :: "v"(base + 2 * k), "v"(pk) : "memory");
    }
}

// ---------------- finish conv1 (root+bias+elu) and pool1 (pairwise max) + pos mean
__global__ __launch_bounds__(256) void pool1_kernel(
    const unsigned short* __restrict__ agg1b, const float* __restrict__ x,
    const float* __restrict__ root1, const float* __restrict__ bias1,
    const float* __restrict__ pos, float* __restrict__ x1, float* __restrict__ pos1)
{
    int t = blockIdx.x * blockDim.x + threadIdx.x;
    if (t >= N1P * C1) return;
    int j = t >> 5, o = t & 31;
    int na = 2 * j, nb = 2 * j + 1;
    float r = root1[o], bo = bias1[o];
    float ha = elu1(bf2f(agg1b[(size_t)na * C1 + o]) + x[na] * r + bo);
    float hb = elu1(bf2f(agg1b[(size_t)nb * C1 + o]) + x[nb] * r + bo);
    x1[t] = fmaxf(ha, hb);
    if (o < 2) pos1[j * 2 + o] = 0.5f * (pos[na * 2 + o] + pos[nb * 2 + o]);
}

// ---------------- global max|cart| over pooled edges
__global__ __launch_bounds__(256) void maxabs_kernel(
    const int* __restrict__ ei2, const float* __restrict__ pos1,
    unsigned int* __restrict__ maxbits)
{
    int e = blockIdx.x * blockDim.x + threadIdx.x;
    float m = 0.f;
    if (e < E2P) {
        int s = ei2[e], d = ei2[E2P + e];
        float c0 = pos1[2 * s] - pos1[2 * d];
        float c1 = pos1[2 * s + 1] - pos1[2 * d + 1];
        m = fmaxf(fabsf(c0), fabsf(c1));
    }
#pragma unroll
    for (int off = 32; off; off >>= 1)
        m = fmaxf(m, __shfl_down(m, off));
    if ((threadIdx.x & 63) == 0)
        atomicMax(maxbits, __float_as_uint(m));
}

// ---------------- build conv2 B matrix [832][64] in MFMA fragment layout, bf16
// Bg element index: ((kt*4 + nb)*64 + lane)*8 + j  = B[kt*32 + (lane>>4)*8 + j][nb*16 + (lane&15)]
__global__ __launch_bounds__(256) void bgbuild_kernel(
    const float* __restrict__ w2, const float* __restrict__ b2,
    unsigned int* __restrict__ Bg)
{
    int idx = blockIdx.x * 256 + threadIdx.x;           // pair index, 26624 total
    if (idx >= 26 * 4 * 64 * 4) return;
    int g0 = idx * 2;
    int j = g0 & 7;
    int l = (g0 >> 3) & 63;
    int nb = (g0 >> 9) & 3;
    int kt = g0 >> 11;
    int k = kt * 32 + (l >> 4) * 8 + j;
    int o = nb * 16 + (l & 15);
    float v0, v1;
    if (k < 800) { v0 = w2[k * 64 + o]; v1 = w2[(k + 1) * 64 + o]; }
    else         { v0 = b2[(k - 800) * 64 + o]; v1 = b2[(k - 799) * 64 + o]; }
    Bg[idx] = pk_bf16(v0, v1);
}

// ---------------- conv2 via MFMA: 64 edges/block, 4 waves x (16 edges x 64 cols), 26 K-steps
__global__ __launch_bounds__(256) void conv2_kernel(
    const int* __restrict__ ei2, const float* __restrict__ pos1,
    const float* __restrict__ x1,
    const float* __restrict__ w1, const float* __restrict__ b1,
    const unsigned int* __restrict__ maxbits,
    const unsigned int* __restrict__ Bg,
    float* __restrict__ agg2)
{
    __shared__ __align__(16) unsigned short xs_lds[64][40];  // bf16 x1[src], row pad 80B
    __shared__ float hid_lds[64][26];
    __shared__ int dst_lds[64];

    int tid = threadIdx.x;
    int tile = blockIdx.x * 64;

    // phase 1a: stage x1[src] as bf16 (4 threads per edge, 8 floats each)
    {
        int le = tid >> 2, q = tid & 3;
        int ge = tile + le;
        float xf[8] = {0, 0, 0, 0, 0, 0, 0, 0};
        if (ge < E2P) {
            int s = ei2[ge];
            const float* xp = x1 + (size_t)s * C1 + q * 8;
            f32x4 v0 = *(const f32x4*)xp;
            f32x4 v1 = *(const f32x4*)(xp + 4);
            xf[0] = v0.x; xf[1] = v0.y; xf[2] = v0.z; xf[3] = v0.w;
            xf[4] = v1.x; xf[5] = v1.y; xf[6] = v1.z; xf[7] = v1.w;
        }
        int4v p;
        p.x = pk_bf16(xf[0], xf[1]); p.y = pk_bf16(xf[2], xf[3]);
        p.z = pk_bf16(xf[4], xf[5]); p.w = pk_bf16(xf[6], xf[7]);
        *(int4v*)&xs_lds[le][q * 8] = p;
    }
    // phase 1b: per-edge hid[25] fp32 (+ dst)
    if (tid < 64) {
        int ge = tile + tid;
        if (ge < E2P) {
            int s = ei2[ge], d = ei2[E2P + ge];
            dst_lds[tid] = d;
            float inv = 0.5f / __uint_as_float(maxbits[0]);
            float a0 = (pos1[2 * s] - pos1[2 * d]) * inv + 0.5f;
            float a1 = (pos1[2 * s + 1] - pos1[2 * d + 1]) * inv + 0.5f;
#pragma unroll
            for (int h = 0; h < HIDN; ++h) {
                float v = fmaf(a0, w1[h], fmaf(a1, w1[HIDN + h], b1[h]));
                hid_lds[tid][h] = fmaxf(v, 0.f);
            }
        } else {
            dst_lds[tid] = 0;
#pragma unroll
            for (int h = 0; h < HIDN; ++h) hid_lds[tid][h] = 0.f;
        }
    }
    __syncthreads();

    // phase 2: K-loop
    int lane = tid & 63, wave = tid >> 6;
    int c = lane & 15, rg = lane >> 4;
    int erow = wave * 16 + c;             // A-operand row (edge within tile)

    FragU xv; xv.i = *(const int4v*)&xs_lds[erow][rg * 8];   // loop-invariant
    float xf[8];
#pragma unroll
    for (int g = 0; g < 4; ++g) {
        unsigned int u = (unsigned int)xv.i[g];
        xf[2 * g]     = __uint_as_float(u << 16);
        xf[2 * g + 1] = __uint_as_float(u & 0xffff0000u);
    }

    f32x4 acc[4];
#pragma unroll
    for (int nb = 0; nb < 4; ++nb) acc[nb] = (f32x4){0.f, 0.f, 0.f, 0.f};

    const int4v* Bg4 = (const int4v*)Bg;
#pragma unroll 2
    for (int kt = 0; kt < 25; ++kt) {
        float hv = hid_lds[erow][kt];
        FragU af;
        af.i.x = pk_bf16(hv * xf[0], hv * xf[1]);
        af.i.y = pk_bf16(hv * xf[2], hv * xf[3]);
        af.i.z = pk_bf16(hv * xf[4], hv * xf[5]);
        af.i.w = pk_bf16(hv * xf[6], hv * xf[7]);
#pragma unroll
        for (int nb = 0; nb < 4; ++nb) {
            FragU bf;
            bf.i = Bg4[(kt * 4 + nb) * 64 + lane];
            acc[nb] = __builtin_amdgcn_mfma_f32_16x16x32_bf16(af.s, bf.s, acc[nb], 0, 0, 0);
        }
    }
    {   // kt = 25: b2 term, A = xs directly
        FragU af; af.i = xv.i;
#pragma unroll
        for (int nb = 0; nb < 4; ++nb) {
            FragU bf;
            bf.i = Bg4[(25 * 4 + nb) * 64 + lane];
            acc[nb] = __builtin_amdgcn_mfma_f32_16x16x32_bf16(af.s, bf.s, acc[nb], 0, 0, 0);
        }
    }

    // epilogue: C row = rg*4 + j, col = nb*16 + c
#pragma unroll
    for (int j = 0; j < 4; ++j) {
        int le = wave * 16 + rg * 4 + j;
        int ge = tile + le;
        if (ge < E2P) {
            int d = dst_lds[le];
            float* dp = agg2 + (size_t)d * C2 + c;
#pragma unroll
            for (int nb = 0; nb < 4; ++nb)
                atomicAdd(dp + nb * 16, acc[nb][j]);
        }
    }
}

// ---------------- finish conv2 (root2+bias2+elu), pool2 (pairwise max), per-graph mean
__global__ __launch_bounds__(256) void pool2_kernel(
    const float* __restrict__ agg2, const float* __restrict__ x1,
    const float* __restrict__ root2, const float* __restrict__ bias2,
    float* __restrict__ g)
{
    int b = blockIdx.x;
    int w = threadIdx.x >> 6, o = threadIdx.x & 63;
    __shared__ float part[4][C2];
    float sum = 0.f;
    for (int jj = w; jj < 50; jj += 4) {
        int j = b * 50 + jj;
        float hv[2];
#pragma unroll
        for (int t = 0; t < 2; ++t) {
            int n = 2 * j + t;
            float a = agg2[(size_t)n * C2 + o] + bias2[o];
#pragma unroll
            for (int i = 0; i < C1; ++i)
                a = fmaf(x1[(size_t)n * C1 + i], root2[i * C2 + o], a);
            hv[t] = elu1(a);
        }
        sum += fmaxf(hv[0], hv[1]);
    }
    part[w][o] = sum;
    __syncthreads();
    if (w == 0) {
        float s2 = part[0][o] + part[1][o] + part[2][o] + part[3][o];
        g[b * C2 + o] = s2 * (1.f / 50.f);
    }
}

// ---------------- FC head
__global__ __launch_bounds__(128) void head_kernel(
    const float* __restrict__ g,
    const float* __restrict__ fc1w, const float* __restrict__ fc1b,
    const float* __restrict__ fc2w, const float* __restrict__ fc2b,
    float* __restrict__ out)
{
    int b = blockIdx.x;
    int t = threadIdx.x;
    __shared__ float gs[C2];
    __shared__ float zs[128];
    __shared__ float ls[NCLS];
    if (t < C2) gs[t] = g[b * C2 + t];
    __syncthreads();
    float z = fc1b[t];
#pragma unroll
    for (int i = 0; i < C2; ++i) z = fmaf(gs[i], fc1w[i * 128 + t], z);
    zs[t] = elu1(z);
    __syncthreads();
    if (t < NCLS) {
        float l = fc2b[t];
#pragma unroll
        for (int k = 0; k < 128; ++k) l = fmaf(zs[k], fc2w[k * NCLS + t], l);
        ls[t] = l;
    }
    __syncthreads();
    if (t < NCLS) {
        float mx = ls[0];
#pragma unroll
        for (int c = 1; c < NCLS; ++c) mx = fmaxf(mx, ls[c]);
        float se = 0.f;
#pragma unroll
        for (int c = 0; c < NCLS; ++c) se += expf(ls[c] - mx);
        out[b * NCLS + t] = ls[t] - mx - logf(se);
    }
}

extern "C" void kernel_launch(void* const* d_in, const int* in_sizes, int n_in,
                              void* d_out, int out_size, void* d_ws, size_t ws_size,
                              hipStream_t stream)
{
    const float* x    = (const float*)d_in[0];
    const float* pos  = (const float*)d_in[1];
    const int*   ei   = (const int*)d_in[2];
    const float* ea   = (const float*)d_in[3];
    const int*   ei2  = (const int*)d_in[6];
    const float* n1w1 = (const float*)d_in[8];
    const float* n1b1 = (const float*)d_in[9];
    const float* n1w2 = (const float*)d_in[10];
    const float* n1b2 = (const float*)d_in[11];
    const float* root1= (const float*)d_in[12];
    const float* bias1= (const float*)d_in[13];
    const float* n2w1 = (const float*)d_in[14];
    const float* n2b1 = (const float*)d_in[15];
    const float* n2w2 = (const float*)d_in[16];
    const float* n2b2 = (const float*)d_in[17];
    const float* root2= (const float*)d_in[18];
    const float* bias2= (const float*)d_in[19];
    const float* fc1w = (const float*)d_in[20];
    const float* fc1b = (const float*)d_in[21];
    const float* fc2w = (const float*)d_in[22];
    const float* fc2b = (const float*)d_in[23];
    float* out = (float*)d_out;

    char* w = (char*)d_ws;
    unsigned short* agg1b = (unsigned short*)w;  w += (size_t)N_NODES * C1 * 2;   // 12.8 MB
    float* x1   = (float*)w;                     w += (size_t)N1P * C1 * 4;       // 12.8 MB
    float* pos1 = (float*)w;                     w += (size_t)N1P * 2 * 4;        // 0.8 MB
    unsigned int* maxbits = (unsigned int*)w;    w += 256;
    float* agg2 = (float*)w;                     w += (size_t)N1P * C2 * 4;       // 25.6 MB
    float* g    = (float*)w;                     w += (size_t)BGR * C2 * 4;
    unsigned int* Bg = (unsigned int*)w;         w += 26624 * 4;

    hipMemsetAsync(agg1b, 0, (size_t)N_NODES * C1 * 2, stream);
    hipMemsetAsync(agg2, 0, (size_t)N1P * C2 * 4, stream);
    hipMemsetAsync(maxbits, 0, 256, stream);

    bgbuild_kernel<<<104, 256, 0, stream>>>(n2w2, n2b2, Bg);
    conv1_kernel<<<E1 / 256, 256, 0, stream>>>(x, ea, ei, n1w1, n1b1, n1w2, n1b2, agg1b);
    pool1_kernel<<<(N1P * C1 + 255) / 256, 256, 0, stream>>>(agg1b, x, root1, bias1, pos, x1, pos1);
    maxabs_kernel<<<(E2P + 255) / 256, 256, 0, stream>>>(ei2, pos1, maxbits);
    conv2_kernel<<<(E2P + 63) / 64, 256, 0, stream>>>(ei2, pos1, x1, n2w1, n2b1, maxbits, Bg, agg2);
    pool2_kernel<<<BGR, 256, 0, stream>>>(agg2, x1, root2, bias2, g);
    head_kernel<<<BGR, 128, 0, stream>>>(g, fc1w, fc1b, fc2w, fc2b, out);
}

// Round 3
// 329.214 us; speedup vs baseline: 4.3300x; 4.3300x over previous
//
#include <hip/hip_runtime.h>
#include <hip/hip_bf16.h>

#define N_NODES 200000
#define E1 1600000
#define N1P 100000
#define E2P 100000
#define N2P 50000
#define BGR 1000
#define C1 32
#define C2 64
#define HIDN 25
#define NCLS 10

typedef short short8 __attribute__((ext_vector_type(8)));
typedef int int4v __attribute__((ext_vector_type(4)));
typedef float f32x4 __attribute__((ext_vector_type(4)));
typedef float f32x2 __attribute__((ext_vector_type(2)));

union FragU { int4v i; short8 s; };

__device__ __forceinline__ float elu1(float v) {
    return v > 0.f ? v : expm1f(v);
}
__device__ __forceinline__ unsigned int pk_bf16(float a, float b) {
    unsigned int r;
    asm("v_cvt_pk_bf16_f32 %0, %1, %2" : "=v"(r) : "v"(a), "v"(b));
    return r;
}

// ---------------- conv1: thread per (edge, channel). 32 lanes own one edge's
// 128B agg row -> each wave atomic instruction = 2 edges x 1 full cacheline.
__global__ __launch_bounds__(256) void conv1_kernel(
    const float* __restrict__ x, const float* __restrict__ ea,
    const int* __restrict__ ei,
    const float* __restrict__ w1, const float* __restrict__ b1,
    const float* __restrict__ w2, const float* __restrict__ b2,
    float* __restrict__ agg1)
{
    int t = blockIdx.x * 256 + threadIdx.x;
    int e = t >> 5;            // edge id (E1*32 == 51.2M threads exactly)
    int o = t & 31;            // output channel
    f32x2 a = ((const f32x2*)ea)[e];
    int s = ei[e], d = ei[E1 + e];
    float xv = x[s];
    float m = b2[o];
#pragma unroll
    for (int h = 0; h < HIDN; ++h) {
        float v = fmaf(a.x, w1[h], fmaf(a.y, w1[HIDN + h], b1[h]));
        v = fmaxf(v, 0.f);
        m = fmaf(v, w2[h * C1 + o], m);
    }
    atomicAdd(agg1 + (size_t)d * C1 + o, m * xv);
}

// ---------------- finish conv1 (root+bias+elu) and pool1 (pairwise max) + pos mean
__global__ __launch_bounds__(256) void pool1_kernel(
    const float* __restrict__ agg1, const float* __restrict__ x,
    const float* __restrict__ root1, const float* __restrict__ bias1,
    const float* __restrict__ pos, float* __restrict__ x1, float* __restrict__ pos1)
{
    int t = blockIdx.x * blockDim.x + threadIdx.x;
    if (t >= N1P * C1) return;
    int j = t >> 5, o = t & 31;
    int na = 2 * j, nb = 2 * j + 1;
    float r = root1[o], bo = bias1[o];
    float ha = elu1(agg1[(size_t)na * C1 + o] + x[na] * r + bo);
    float hb = elu1(agg1[(size_t)nb * C1 + o] + x[nb] * r + bo);
    x1[t] = fmaxf(ha, hb);
    if (o < 2) pos1[j * 2 + o] = 0.5f * (pos[na * 2 + o] + pos[nb * 2 + o]);
}

// ---------------- global max|cart| over pooled edges
__global__ __launch_bounds__(256) void maxabs_kernel(
    const int* __restrict__ ei2, const float* __restrict__ pos1,
    unsigned int* __restrict__ maxbits)
{
    int e = blockIdx.x * blockDim.x + threadIdx.x;
    float m = 0.f;
    if (e < E2P) {
        int s = ei2[e], d = ei2[E2P + e];
        float c0 = pos1[2 * s] - pos1[2 * d];
        float c1 = pos1[2 * s + 1] - pos1[2 * d + 1];
        m = fmaxf(fabsf(c0), fabsf(c1));
    }
#pragma unroll
    for (int off = 32; off; off >>= 1)
        m = fmaxf(m, __shfl_down(m, off));
    if ((threadIdx.x & 63) == 0)
        atomicMax(maxbits, __float_as_uint(m));
}

// ---------------- build conv2 B matrix [832][64] in MFMA fragment layout, bf16
// Bg element index: ((kt*4 + nb)*64 + lane)*8 + j  = B[kt*32 + (lane>>4)*8 + j][nb*16 + (lane&15)]
__global__ __launch_bounds__(256) void bgbuild_kernel(
    const float* __restrict__ w2, const float* __restrict__ b2,
    unsigned int* __restrict__ Bg)
{
    int idx = blockIdx.x * 256 + threadIdx.x;           // pair index, 26624 total
    if (idx >= 26 * 4 * 64 * 4) return;
    int g0 = idx * 2;
    int j = g0 & 7;
    int l = (g0 >> 3) & 63;
    int nb = (g0 >> 9) & 3;
    int kt = g0 >> 11;
    int k = kt * 32 + (l >> 4) * 8 + j;
    int o = nb * 16 + (l & 15);
    float v0, v1;
    if (k < 800) { v0 = w2[k * 64 + o]; v1 = w2[(k + 1) * 64 + o]; }
    else         { v0 = b2[(k - 800) * 64 + o]; v1 = b2[(k - 799) * 64 + o]; }
    Bg[idx] = pk_bf16(v0, v1);
}

// ---------------- conv2 via MFMA: 64 edges/block, 4 waves x (16 edges x 64 cols), 26 K-steps
__global__ __launch_bounds__(256) void conv2_kernel(
    const int* __restrict__ ei2, const float* __restrict__ pos1,
    const float* __restrict__ x1,
    const float* __restrict__ w1, const float* __restrict__ b1,
    const unsigned int* __restrict__ maxbits,
    const unsigned int* __restrict__ Bg,
    float* __restrict__ agg2)
{
    __shared__ __align__(16) unsigned short xs_lds[64][40];  // bf16 x1[src], row pad 80B
    __shared__ float hid_lds[64][26];
    __shared__ int dst_lds[64];

    int tid = threadIdx.x;
    int tile = blockIdx.x * 64;

    // phase 1a: stage x1[src] as bf16 (4 threads per edge, 8 floats each)
    {
        int le = tid >> 2, q = tid & 3;
        int ge = tile + le;
        float xf[8] = {0, 0, 0, 0, 0, 0, 0, 0};
        if (ge < E2P) {
            int s = ei2[ge];
            const float* xp = x1 + (size_t)s * C1 + q * 8;
            f32x4 v0 = *(const f32x4*)xp;
            f32x4 v1 = *(const f32x4*)(xp + 4);
            xf[0] = v0.x; xf[1] = v0.y; xf[2] = v0.z; xf[3] = v0.w;
            xf[4] = v1.x; xf[5] = v1.y; xf[6] = v1.z; xf[7] = v1.w;
        }
        int4v p;
        p.x = pk_bf16(xf[0], xf[1]); p.y = pk_bf16(xf[2], xf[3]);
        p.z = pk_bf16(xf[4], xf[5]); p.w = pk_bf16(xf[6], xf[7]);
        *(int4v*)&xs_lds[le][q * 8] = p;
    }
    // phase 1b: per-edge hid[25] fp32 (+ dst)
    if (tid < 64) {
        int ge = tile + tid;
        if (ge < E2P) {
            int s = ei2[ge], d = ei2[E2P + ge];
            dst_lds[tid] = d;
            float inv = 0.5f / __uint_as_float(maxbits[0]);
            float a0 = (pos1[2 * s] - pos1[2 * d]) * inv + 0.5f;
            float a1 = (pos1[2 * s + 1] - pos1[2 * d + 1]) * inv + 0.5f;
#pragma unroll
            for (int h = 0; h < HIDN; ++h) {
                float v = fmaf(a0, w1[h], fmaf(a1, w1[HIDN + h], b1[h]));
                hid_lds[tid][h] = fmaxf(v, 0.f);
            }
        } else {
            dst_lds[tid] = 0;
#pragma unroll
            for (int h = 0; h < HIDN; ++h) hid_lds[tid][h] = 0.f;
        }
    }
    __syncthreads();

    // phase 2: K-loop
    int lane = tid & 63, wave = tid >> 6;
    int c = lane & 15, rg = lane >> 4;
    int erow = wave * 16 + c;             // A-operand row (edge within tile)

    FragU xv; xv.i = *(const int4v*)&xs_lds[erow][rg * 8];   // loop-invariant
    float xf[8];
#pragma unroll
    for (int g = 0; g < 4; ++g) {
        unsigned int u = (unsigned int)xv.i[g];
        xf[2 * g]     = __uint_as_float(u << 16);
        xf[2 * g + 1] = __uint_as_float(u & 0xffff0000u);
    }

    f32x4 acc[4];
#pragma unroll
    for (int nb = 0; nb < 4; ++nb) acc[nb] = (f32x4){0.f, 0.f, 0.f, 0.f};

    const int4v* Bg4 = (const int4v*)Bg;
#pragma unroll 2
    for (int kt = 0; kt < 25; ++kt) {
        float hv = hid_lds[erow][kt];
        FragU af;
        af.i.x = pk_bf16(hv * xf[0], hv * xf[1]);
        af.i.y = pk_bf16(hv * xf[2], hv * xf[3]);
        af.i.z = pk_bf16(hv * xf[4], hv * xf[5]);
        af.i.w = pk_bf16(hv * xf[6], hv * xf[7]);
#pragma unroll
        for (int nb = 0; nb < 4; ++nb) {
            FragU bf;
            bf.i = Bg4[(kt * 4 + nb) * 64 + lane];
            acc[nb] = __builtin_amdgcn_mfma_f32_16x16x32_bf16(af.s, bf.s, acc[nb], 0, 0, 0);
        }
    }
    {   // kt = 25: b2 term, A = xs directly
        FragU af; af.i = xv.i;
#pragma unroll
        for (int nb = 0; nb < 4; ++nb) {
            FragU bf;
            bf.i = Bg4[(25 * 4 + nb) * 64 + lane];
            acc[nb] = __builtin_amdgcn_mfma_f32_16x16x32_bf16(af.s, bf.s, acc[nb], 0, 0, 0);
        }
    }

    // epilogue: C row = rg*4 + j, col = nb*16 + c
#pragma unroll
    for (int j = 0; j < 4; ++j) {
        int le = wave * 16 + rg * 4 + j;
        int ge = tile + le;
        if (ge < E2P) {
            int d = dst_lds[le];
            float* dp = agg2 + (size_t)d * C2 + c;
#pragma unroll
            for (int nb = 0; nb < 4; ++nb)
                atomicAdd(dp + nb * 16, acc[nb][j]);
        }
    }
}

// ---------------- finish conv2 (root2+bias2+elu), pool2 (pairwise max), per-graph mean
__global__ __launch_bounds__(256) void pool2_kernel(
    const float* __restrict__ agg2, const float* __restrict__ x1,
    const float* __restrict__ root2, const float* __restrict__ bias2,
    float* __restrict__ g)
{
    int b = blockIdx.x;
    int w = threadIdx.x >> 6, o = threadIdx.x & 63;
    __shared__ float part[4][C2];
    float sum = 0.f;
    for (int jj = w; jj < 50; jj += 4) {
        int j = b * 50 + jj;
        float hv[2];
#pragma unroll
        for (int t = 0; t < 2; ++t) {
            int n = 2 * j + t;
            float a = agg2[(size_t)n * C2 + o] + bias2[o];
#pragma unroll
            for (int i = 0; i < C1; ++i)
                a = fmaf(x1[(size_t)n * C1 + i], root2[i * C2 + o], a);
            hv[t] = elu1(a);
        }
        sum += fmaxf(hv[0], hv[1]);
    }
    part[w][o] = sum;
    __syncthreads();
    if (w == 0) {
        float s2 = part[0][o] + part[1][o] + part[2][o] + part[3][o];
        g[b * C2 + o] = s2 * (1.f / 50.f);
    }
}

// ---------------- FC head
__global__ __launch_bounds__(128) void head_kernel(
    const float* __restrict__ g,
    const float* __restrict__ fc1w, const float* __restrict__ fc1b,
    const float* __restrict__ fc2w, const float* __restrict__ fc2b,
    float* __restrict__ out)
{
    int b = blockIdx.x;
    int t = threadIdx.x;
    __shared__ float gs[C2];
    __shared__ float zs[128];
    __shared__ float ls[NCLS];
    if (t < C2) gs[t] = g[b * C2 + t];
    __syncthreads();
    float z = fc1b[t];
#pragma unroll
    for (int i = 0; i < C2; ++i) z = fmaf(gs[i], fc1w[i * 128 + t], z);
    zs[t] = elu1(z);
    __syncthreads();
    if (t < NCLS) {
        float l = fc2b[t];
#pragma unroll
        for (int k = 0; k < 128; ++k) l = fmaf(zs[k], fc2w[k * NCLS + t], l);
        ls[t] = l;
    }
    __syncthreads();
    if (t < NCLS) {
        float mx = ls[0];
#pragma unroll
        for (int c = 1; c < NCLS; ++c) mx = fmaxf(mx, ls[c]);
        float se = 0.f;
#pragma unroll
        for (int c = 0; c < NCLS; ++c) se += expf(ls[c] - mx);
        out[b * NCLS + t] = ls[t] - mx - logf(se);
    }
}

extern "C" void kernel_launch(void* const* d_in, const int* in_sizes, int n_in,
                              void* d_out, int out_size, void* d_ws, size_t ws_size,
                              hipStream_t stream)
{
    const float* x    = (const float*)d_in[0];
    const float* pos  = (const float*)d_in[1];
    const int*   ei   = (const int*)d_in[2];
    const float* ea   = (const float*)d_in[3];
    const int*   ei2  = (const int*)d_in[6];
    const float* n1w1 = (const float*)d_in[8];
    const float* n1b1 = (const float*)d_in[9];
    const float* n1w2 = (const float*)d_in[10];
    const float* n1b2 = (const float*)d_in[11];
    const float* root1= (const float*)d_in[12];
    const float* bias1= (const float*)d_in[13];
    const float* n2w1 = (const float*)d_in[14];
    const float* n2b1 = (const float*)d_in[15];
    const float* n2w2 = (const float*)d_in[16];
    const float* n2b2 = (const float*)d_in[17];
    const float* root2= (const float*)d_in[18];
    const float* bias2= (const float*)d_in[19];
    const float* fc1w = (const float*)d_in[20];
    const float* fc1b = (const float*)d_in[21];
    const float* fc2w = (const float*)d_in[22];
    const float* fc2b = (const float*)d_in[23];
    float* out = (float*)d_out;

    char* w = (char*)d_ws;
    float* agg1 = (float*)w;                     w += (size_t)N_NODES * C1 * 4;   // 25.6 MB
    float* x1   = (float*)w;                     w += (size_t)N1P * C1 * 4;       // 12.8 MB
    float* pos1 = (float*)w;                     w += (size_t)N1P * 2 * 4;        // 0.8 MB
    unsigned int* maxbits = (unsigned int*)w;    w += 256;
    float* agg2 = (float*)w;                     w += (size_t)N1P * C2 * 4;       // 25.6 MB
    float* g    = (float*)w;                     w += (size_t)BGR * C2 * 4;
    unsigned int* Bg = (unsigned int*)w;         w += 26624 * 4;

    hipMemsetAsync(agg1, 0, (size_t)N_NODES * C1 * 4, stream);
    hipMemsetAsync(agg2, 0, (size_t)N1P * C2 * 4, stream);
    hipMemsetAsync(maxbits, 0, 256, stream);

    bgbuild_kernel<<<104, 256, 0, stream>>>(n2w2, n2b2, Bg);
    conv1_kernel<<<E1 / 8, 256, 0, stream>>>(x, ea, ei, n1w1, n1b1, n1w2, n1b2, agg1);
    pool1_kernel<<<(N1P * C1 + 255) / 256, 256, 0, stream>>>(agg1, x, root1, bias1, pos, x1, pos1);
    maxabs_kernel<<<(E2P + 255) / 256, 256, 0, stream>>>(ei2, pos1, maxbits);
    conv2_kernel<<<(E2P + 63) / 64, 256, 0, stream>>>(ei2, pos1, x1, n2w1, n2b1, maxbits, Bg, agg2);
    pool2_kernel<<<BGR, 256, 0, stream>>>(agg2, x1, root2, bias2, g);
    head_kernel<<<BGR, 128, 0, stream>>>(g, fc1w, fc1b, fc2w, fc2b, out);
}

// Round 4
// 292.484 us; speedup vs baseline: 4.8738x; 1.1256x over previous
//
#include <hip/hip_runtime.h>
#include <hip/hip_bf16.h>

#define N_NODES 200000
#define E1 1600000
#define N1P 100000
#define E2P 100000
#define N2P 50000
#define BGR 1000
#define C1 32
#define C2 64
#define HIDN 25
#define NCLS 10

typedef short short8 __attribute__((ext_vector_type(8)));
typedef int int4v __attribute__((ext_vector_type(4)));
typedef float f32x4 __attribute__((ext_vector_type(4)));
typedef float f32x2 __attribute__((ext_vector_type(2)));

union FragU { int4v i; short8 s; };

__device__ __forceinline__ float elu1(float v) {
    return v > 0.f ? v : expm1f(v);
}
__device__ __forceinline__ unsigned int pk_bf16(float a, float b) {
    unsigned int r;
    asm("v_cvt_pk_bf16_f32 %0, %1, %2" : "=v"(r) : "v"(a), "v"(b));
    return r;
}

// ---------------- build conv1 B matrix [32][32] (W2ext: rows 0-24 = w2, row 25 = b2,
// rows 26-31 = 0) as MFMA B-fragments: W2f[(nb*64 + lane)*4 + slot]
__global__ __launch_bounds__(256) void bgbuild1_kernel(
    const float* __restrict__ w2, const float* __restrict__ b2,
    unsigned int* __restrict__ W2f)
{
    int q = blockIdx.x * 256 + threadIdx.x;     // 512 u32 total
    if (q >= 512) return;
    int jj = q & 3, l = (q >> 2) & 63, nb = q >> 8;
    int k0 = (l >> 4) * 8 + 2 * jj;
    int o = nb * 16 + (l & 15);
    float v0 = (k0 < 25) ? w2[k0 * 32 + o] : (k0 == 25 ? b2[o] : 0.f);
    int k1 = k0 + 1;
    float v1 = (k1 < 25) ? w2[k1 * 32 + o] : (k1 == 25 ? b2[o] : 0.f);
    W2f[q] = pk_bf16(v0, v1);
}

// ---------------- conv1 via MFMA: 256 edges/block; per-edge hid computed ONCE;
// A row = [xv*hid[0..24], xv] (K padded to 32); 2 MFMAs per 16-edge tile.
__global__ __launch_bounds__(256) void conv1_kernel(
    const float* __restrict__ x, const float* __restrict__ ea,
    const int* __restrict__ ei,
    const float* __restrict__ w1, const float* __restrict__ b1,
    const unsigned int* __restrict__ W2f,
    float* __restrict__ agg1)
{
    __shared__ unsigned int afrag[16][4][64];   // [tile][u32-slot][lane] = 16 KB
    __shared__ int dst_lds[256];

    int t = threadIdx.x;
    int e = blockIdx.x * 256 + t;               // E1 % 256 == 0, no guard
    f32x2 a = ((const f32x2*)ea)[e];
    int s = ei[e], d = ei[E1 + e];
    float xv = x[s];
    dst_lds[t] = d;

    float v[26];
#pragma unroll
    for (int h = 0; h < HIDN; ++h) {
        float u = fmaf(a.x, w1[h], fmaf(a.y, w1[HIDN + h], b1[h]));
        v[h] = fmaxf(u, 0.f) * xv;
    }
    v[25] = xv;

    int tile = t >> 4, r = t & 15;
#pragma unroll
    for (int p = 0; p < 13; ++p) {              // pair p covers k = 2p, 2p+1
        int g = p >> 2, j = p & 3;
        afrag[tile][j][g * 16 + r] = pk_bf16(v[2 * p], v[2 * p + 1]);
    }
    afrag[tile][1][48 + r] = 0;                 // k = 26..31 zero (avoid NaN garbage)
    afrag[tile][2][48 + r] = 0;
    afrag[tile][3][48 + r] = 0;
    __syncthreads();

    int lane = t & 63, wave = t >> 6;
    FragU bf0, bf1;
    bf0.i = *(const int4v*)(W2f + lane * 4);
    bf1.i = *(const int4v*)(W2f + (64 + lane) * 4);
    int c = lane & 15, rg = lane >> 4;

#pragma unroll
    for (int ti = 0; ti < 4; ++ti) {
        int tl = wave * 4 + ti;
        FragU af;
        af.i.x = afrag[tl][0][lane];
        af.i.y = afrag[tl][1][lane];
        af.i.z = afrag[tl][2][lane];
        af.i.w = afrag[tl][3][lane];
        f32x4 a0 = (f32x4){0.f, 0.f, 0.f, 0.f};
        f32x4 a1 = (f32x4){0.f, 0.f, 0.f, 0.f};
        a0 = __builtin_amdgcn_mfma_f32_16x16x32_bf16(af.s, bf0.s, a0, 0, 0, 0);
        a1 = __builtin_amdgcn_mfma_f32_16x16x32_bf16(af.s, bf1.s, a1, 0, 0, 0);
#pragma unroll
        for (int jj = 0; jj < 4; ++jj) {
            int le = tl * 16 + rg * 4 + jj;
            float* dp = agg1 + (size_t)dst_lds[le] * C1;
            atomicAdd(dp + c, a0[jj]);
            atomicAdd(dp + 16 + c, a1[jj]);
        }
    }
}

// ---------------- finish conv1 (root+bias+elu) and pool1 (pairwise max) + pos mean
__global__ __launch_bounds__(256) void pool1_kernel(
    const float* __restrict__ agg1, const float* __restrict__ x,
    const float* __restrict__ root1, const float* __restrict__ bias1,
    const float* __restrict__ pos, float* __restrict__ x1, float* __restrict__ pos1)
{
    int t = blockIdx.x * blockDim.x + threadIdx.x;
    if (t >= N1P * C1) return;
    int j = t >> 5, o = t & 31;
    int na = 2 * j, nb = 2 * j + 1;
    float r = root1[o], bo = bias1[o];
    float ha = elu1(agg1[(size_t)na * C1 + o] + x[na] * r + bo);
    float hb = elu1(agg1[(size_t)nb * C1 + o] + x[nb] * r + bo);
    x1[t] = fmaxf(ha, hb);
    if (o < 2) pos1[j * 2 + o] = 0.5f * (pos[na * 2 + o] + pos[nb * 2 + o]);
}

// ---------------- global max|cart| over pooled edges
__global__ __launch_bounds__(256) void maxabs_kernel(
    const int* __restrict__ ei2, const float* __restrict__ pos1,
    unsigned int* __restrict__ maxbits)
{
    int e = blockIdx.x * blockDim.x + threadIdx.x;
    float m = 0.f;
    if (e < E2P) {
        int s = ei2[e], d = ei2[E2P + e];
        float c0 = pos1[2 * s] - pos1[2 * d];
        float c1 = pos1[2 * s + 1] - pos1[2 * d + 1];
        m = fmaxf(fabsf(c0), fabsf(c1));
    }
#pragma unroll
    for (int off = 32; off; off >>= 1)
        m = fmaxf(m, __shfl_down(m, off));
    if ((threadIdx.x & 63) == 0)
        atomicMax(maxbits, __float_as_uint(m));
}

// ---------------- build conv2 B matrix [832][64] in MFMA fragment layout, bf16
__global__ __launch_bounds__(256) void bgbuild_kernel(
    const float* __restrict__ w2, const float* __restrict__ b2,
    unsigned int* __restrict__ Bg)
{
    int idx = blockIdx.x * 256 + threadIdx.x;           // pair index, 26624 total
    if (idx >= 26 * 4 * 64 * 4) return;
    int g0 = idx * 2;
    int j = g0 & 7;
    int l = (g0 >> 3) & 63;
    int nb = (g0 >> 9) & 3;
    int kt = g0 >> 11;
    int k = kt * 32 + (l >> 4) * 8 + j;
    int o = nb * 16 + (l & 15);
    float v0, v1;
    if (k < 800) { v0 = w2[k * 64 + o]; v1 = w2[(k + 1) * 64 + o]; }
    else         { v0 = b2[(k - 800) * 64 + o]; v1 = b2[(k - 799) * 64 + o]; }
    Bg[idx] = pk_bf16(v0, v1);
}

// ---------------- conv2 via MFMA: 256 edges/block, kt-outer loop amortizes B stream
__global__ __launch_bounds__(256) void conv2_kernel(
    const int* __restrict__ ei2, const float* __restrict__ pos1,
    const float* __restrict__ x1,
    const float* __restrict__ w1, const float* __restrict__ b1,
    const unsigned int* __restrict__ maxbits,
    const unsigned int* __restrict__ Bg,
    float* __restrict__ agg2)
{
    __shared__ __align__(16) unsigned short xs_lds[256][40];  // 20 KB
    __shared__ float hid_lds[256][27];                         // 27.6 KB
    __shared__ int dst_lds[256];

    int t = threadIdx.x;
    int ge = blockIdx.x * 256 + t;

    {   // phase 1: per-edge hid + bf16 xs staging
        float inv = 0.5f / __uint_as_float(maxbits[0]);
        int s = 0, d = 0;
        if (ge < E2P) { s = ei2[ge]; d = ei2[E2P + ge]; }
        dst_lds[t] = d;
        float a0 = (pos1[2 * s] - pos1[2 * d]) * inv + 0.5f;
        float a1 = (pos1[2 * s + 1] - pos1[2 * d + 1]) * inv + 0.5f;
#pragma unroll
        for (int h = 0; h < HIDN; ++h) {
            float u = fmaf(a0, w1[h], fmaf(a1, w1[HIDN + h], b1[h]));
            hid_lds[t][h] = fmaxf(u, 0.f);
        }
        const f32x4* xp = (const f32x4*)(x1 + (size_t)s * C1);
#pragma unroll
        for (int q = 0; q < 4; ++q) {
            f32x4 v0 = xp[2 * q];
            f32x4 v1 = xp[2 * q + 1];
            int4v p;
            p.x = pk_bf16(v0.x, v0.y); p.y = pk_bf16(v0.z, v0.w);
            p.z = pk_bf16(v1.x, v1.y); p.w = pk_bf16(v1.z, v1.w);
            *(int4v*)&xs_lds[t][q * 8] = p;
        }
    }
    __syncthreads();

    int lane = t & 63, wave = t >> 6;
    int c = lane & 15, rg = lane >> 4;

    FragU xv4[4];
    float xfl[4][8];
#pragma unroll
    for (int ti = 0; ti < 4; ++ti) {
        int row = (wave * 4 + ti) * 16 + c;
        xv4[ti].i = *(const int4v*)&xs_lds[row][rg * 8];
#pragma unroll
        for (int g2 = 0; g2 < 4; ++g2) {
            unsigned int u = (unsigned int)xv4[ti].i[g2];
            xfl[ti][2 * g2]     = __uint_as_float(u << 16);
            xfl[ti][2 * g2 + 1] = __uint_as_float(u & 0xffff0000u);
        }
    }

    f32x4 acc[4][4];
#pragma unroll
    for (int ti = 0; ti < 4; ++ti)
#pragma unroll
        for (int nb = 0; nb < 4; ++nb)
            acc[ti][nb] = (f32x4){0.f, 0.f, 0.f, 0.f};

    const int4v* Bg4 = (const int4v*)Bg;
#pragma unroll 2
    for (int kt = 0; kt < 25; ++kt) {
        FragU bf[4];
#pragma unroll
        for (int nb = 0; nb < 4; ++nb)
            bf[nb].i = Bg4[(kt * 4 + nb) * 64 + lane];
#pragma unroll
        for (int ti = 0; ti < 4; ++ti) {
            float hv = hid_lds[(wave * 4 + ti) * 16 + c][kt];
            FragU af;
            af.i.x = pk_bf16(hv * xfl[ti][0], hv * xfl[ti][1]);
            af.i.y = pk_bf16(hv * xfl[ti][2], hv * xfl[ti][3]);
            af.i.z = pk_bf16(hv * xfl[ti][4], hv * xfl[ti][5]);
            af.i.w = pk_bf16(hv * xfl[ti][6], hv * xfl[ti][7]);
#pragma unroll
            for (int nb = 0; nb < 4; ++nb)
                acc[ti][nb] = __builtin_amdgcn_mfma_f32_16x16x32_bf16(af.s, bf[nb].s, acc[ti][nb], 0, 0, 0);
        }
    }
    {   // kt = 25: b2 term, A = xs directly
        FragU bf[4];
#pragma unroll
        for (int nb = 0; nb < 4; ++nb)
            bf[nb].i = Bg4[(25 * 4 + nb) * 64 + lane];
#pragma unroll
        for (int ti = 0; ti < 4; ++ti)
#pragma unroll
            for (int nb = 0; nb < 4; ++nb)
                acc[ti][nb] = __builtin_amdgcn_mfma_f32_16x16x32_bf16(xv4[ti].s, bf[nb].s, acc[ti][nb], 0, 0, 0);
    }

    // epilogue
#pragma unroll
    for (int ti = 0; ti < 4; ++ti) {
        int tl = wave * 4 + ti;
#pragma unroll
        for (int jj = 0; jj < 4; ++jj) {
            int le = tl * 16 + rg * 4 + jj;
            if (blockIdx.x * 256 + le < E2P) {
                float* dp = agg2 + (size_t)dst_lds[le] * C2 + c;
#pragma unroll
                for (int nb = 0; nb < 4; ++nb)
                    atomicAdd(dp + nb * 16, acc[ti][nb][jj]);
            }
        }
    }
}

// ---------------- finish conv2 (root2+bias2+elu), pool2 (pairwise max), per-graph mean
__global__ __launch_bounds__(256) void pool2_kernel(
    const float* __restrict__ agg2, const float* __restrict__ x1,
    const float* __restrict__ root2, const float* __restrict__ bias2,
    float* __restrict__ g)
{
    int b = blockIdx.x;
    int w = threadIdx.x >> 6, o = threadIdx.x & 63;
    __shared__ float part[4][C2];
    float sum = 0.f;
    for (int jj = w; jj < 50; jj += 4) {
        int j = b * 50 + jj;
        float hv[2];
#pragma unroll
        for (int t = 0; t < 2; ++t) {
            int n = 2 * j + t;
            float a = agg2[(size_t)n * C2 + o] + bias2[o];
#pragma unroll
            for (int i = 0; i < C1; ++i)
                a = fmaf(x1[(size_t)n * C1 + i], root2[i * C2 + o], a);
            hv[t] = elu1(a);
        }
        sum += fmaxf(hv[0], hv[1]);
    }
    part[w][o] = sum;
    __syncthreads();
    if (w == 0) {
        float s2 = part[0][o] + part[1][o] + part[2][o] + part[3][o];
        g[b * C2 + o] = s2 * (1.f / 50.f);
    }
}

// ---------------- FC head
__global__ __launch_bounds__(128) void head_kernel(
    const float* __restrict__ g,
    const float* __restrict__ fc1w, const float* __restrict__ fc1b,
    const float* __restrict__ fc2w, const float* __restrict__ fc2b,
    float* __restrict__ out)
{
    int b = blockIdx.x;
    int t = threadIdx.x;
    __shared__ float gs[C2];
    __shared__ float zs[128];
    __shared__ float ls[NCLS];
    if (t < C2) gs[t] = g[b * C2 + t];
    __syncthreads();
    float z = fc1b[t];
#pragma unroll
    for (int i = 0; i < C2; ++i) z = fmaf(gs[i], fc1w[i * 128 + t], z);
    zs[t] = elu1(z);
    __syncthreads();
    if (t < NCLS) {
        float l = fc2b[t];
#pragma unroll
        for (int k = 0; k < 128; ++k) l = fmaf(zs[k], fc2w[k * NCLS + t], l);
        ls[t] = l;
    }
    __syncthreads();
    if (t < NCLS) {
        float mx = ls[0];
#pragma unroll
        for (int c = 1; c < NCLS; ++c) mx = fmaxf(mx, ls[c]);
        float se = 0.f;
#pragma unroll
        for (int c = 0; c < NCLS; ++c) se += expf(ls[c] - mx);
        out[b * NCLS + t] = ls[t] - mx - logf(se);
    }
}

extern "C" void kernel_launch(void* const* d_in, const int* in_sizes, int n_in,
                              void* d_out, int out_size, void* d_ws, size_t ws_size,
                              hipStream_t stream)
{
    const float* x    = (const float*)d_in[0];
    const float* pos  = (const float*)d_in[1];
    const int*   ei   = (const int*)d_in[2];
    const float* ea   = (const float*)d_in[3];
    const int*   ei2  = (const int*)d_in[6];
    const float* n1w1 = (const float*)d_in[8];
    const float* n1b1 = (const float*)d_in[9];
    const float* n1w2 = (const float*)d_in[10];
    const float* n1b2 = (const float*)d_in[11];
    const float* root1= (const float*)d_in[12];
    const float* bias1= (const float*)d_in[13];
    const float* n2w1 = (const float*)d_in[14];
    const float* n2b1 = (const float*)d_in[15];
    const float* n2w2 = (const float*)d_in[16];
    const float* n2b2 = (const float*)d_in[17];
    const float* root2= (const float*)d_in[18];
    const float* bias2= (const float*)d_in[19];
    const float* fc1w = (const float*)d_in[20];
    const float* fc1b = (const float*)d_in[21];
    const float* fc2w = (const float*)d_in[22];
    const float* fc2b = (const float*)d_in[23];
    float* out = (float*)d_out;

    char* w = (char*)d_ws;
    float* agg1 = (float*)w;                     w += (size_t)N_NODES * C1 * 4;   // 25.6 MB
    float* x1   = (float*)w;                     w += (size_t)N1P * C1 * 4;       // 12.8 MB
    float* pos1 = (float*)w;                     w += (size_t)N1P * 2 * 4;        // 0.8 MB
    unsigned int* maxbits = (unsigned int*)w;    w += 256;
    float* agg2 = (float*)w;                     w += (size_t)N1P * C2 * 4;       // 25.6 MB
    float* g    = (float*)w;                     w += (size_t)BGR * C2 * 4;
    unsigned int* Bg = (unsigned int*)w;         w += 26624 * 4;
    unsigned int* W2f = (unsigned int*)w;        w += 512 * 4;

    hipMemsetAsync(agg1, 0, (size_t)N_NODES * C1 * 4, stream);
    hipMemsetAsync(agg2, 0, (size_t)N1P * C2 * 4, stream);
    hipMemsetAsync(maxbits, 0, 256, stream);

    bgbuild1_kernel<<<2, 256, 0, stream>>>(n1w2, n1b2, W2f);
    bgbuild_kernel<<<104, 256, 0, stream>>>(n2w2, n2b2, Bg);
    conv1_kernel<<<E1 / 256, 256, 0, stream>>>(x, ea, ei, n1w1, n1b1, W2f, agg1);
    pool1_kernel<<<(N1P * C1 + 255) / 256, 256, 0, stream>>>(agg1, x, root1, bias1, pos, x1, pos1);
    maxabs_kernel<<<(E2P + 255) / 256, 256, 0, stream>>>(ei2, pos1, maxbits);
    conv2_kernel<<<(E2P + 255) / 256, 256, 0, stream>>>(ei2, pos1, x1, n2w1, n2b1, maxbits, Bg, agg2);
    pool2_kernel<<<BGR, 256, 0, stream>>>(agg2, x1, root2, bias2, g);
    head_kernel<<<BGR, 128, 0, stream>>>(g, fc1w, fc1b, fc2w, fc2b, out);
}

// Round 5
// 188.140 us; speedup vs baseline: 7.5768x; 1.5546x over previous
//
#include <hip/hip_runtime.h>
#include <hip/hip_bf16.h>

#define N_NODES 200000
#define E1 1600000
#define N1P 100000
#define E2P 100000
#define N2P 50000
#define BGR 1000
#define C1 32
#define C2 64
#define HIDN 25
#define NCLS 10

typedef short short8 __attribute__((ext_vector_type(8)));
typedef int int4v __attribute__((ext_vector_type(4)));
typedef float f32x4 __attribute__((ext_vector_type(4)));
typedef float f32x2 __attribute__((ext_vector_type(2)));

union FragU { int4v i; short8 s; };

__device__ __forceinline__ float elu1(float v) {
    return v > 0.f ? v : expm1f(v);
}
__device__ __forceinline__ float bf2f(unsigned short u) {
    return __uint_as_float(((unsigned int)u) << 16);
}
__device__ __forceinline__ unsigned int pk_bf16(float a, float b) {
    unsigned int r;
    asm("v_cvt_pk_bf16_f32 %0, %1, %2" : "=v"(r) : "v"(a), "v"(b));
    return r;
}
__device__ __forceinline__ void atomic_pk_bf16(unsigned short* p, unsigned int pk) {
    asm volatile("global_atomic_pk_add_bf16 %0, %1, off" :: "v"(p), "v"(pk) : "memory");
}

// ---------------- build conv1 B [32][32] as MFMA B-fragments with EVEN/ODD column perm:
// MFMA m (m=0,1), col c -> channel 2c+m.  W2f[(m*64 + lane)*4 + slot]
__global__ __launch_bounds__(256) void bgbuild1_kernel(
    const float* __restrict__ w2, const float* __restrict__ b2,
    unsigned int* __restrict__ W2f)
{
    int q = blockIdx.x * 256 + threadIdx.x;     // 512 u32 total
    if (q >= 512) return;
    int jj = q & 3, l = (q >> 2) & 63, m = q >> 8;
    int k0 = (l >> 4) * 8 + 2 * jj;
    int o = 2 * (l & 15) + m;                   // even/odd channel perm
    float v0 = (k0 < 25) ? w2[k0 * 32 + o] : (k0 == 25 ? b2[o] : 0.f);
    int k1 = k0 + 1;
    float v1 = (k1 < 25) ? w2[k1 * 32 + o] : (k1 == 25 ? b2[o] : 0.f);
    W2f[q] = pk_bf16(v0, v1);
}

// ---------------- conv1 via MFMA; epilogue = packed bf16 atomics, full 64B row/instr
__global__ __launch_bounds__(256) void conv1_kernel(
    const float* __restrict__ x, const float* __restrict__ ea,
    const int* __restrict__ ei,
    const float* __restrict__ w1, const float* __restrict__ b1,
    const unsigned int* __restrict__ W2f,
    unsigned short* __restrict__ agg1b)
{
    __shared__ unsigned int afrag[16][4][64];   // [tile][u32-slot][lane] = 16 KB
    __shared__ int dst_lds[256];

    int t = threadIdx.x;
    int e = blockIdx.x * 256 + t;               // E1 % 256 == 0
    f32x2 a = ((const f32x2*)ea)[e];
    int s = ei[e], d = ei[E1 + e];
    float xv = x[s];
    dst_lds[t] = d;

    float v[26];
#pragma unroll
    for (int h = 0; h < HIDN; ++h) {
        float u = fmaf(a.x, w1[h], fmaf(a.y, w1[HIDN + h], b1[h]));
        v[h] = fmaxf(u, 0.f) * xv;
    }
    v[25] = xv;

    int tile = t >> 4, r = t & 15;
#pragma unroll
    for (int p = 0; p < 13; ++p) {              // pair p covers k = 2p, 2p+1
        int g = p >> 2, j = p & 3;
        afrag[tile][j][g * 16 + r] = pk_bf16(v[2 * p], v[2 * p + 1]);
    }
    afrag[tile][1][48 + r] = 0;                 // k = 26..31 zero
    afrag[tile][2][48 + r] = 0;
    afrag[tile][3][48 + r] = 0;
    __syncthreads();

    int lane = t & 63, wave = t >> 6;
    FragU bf0, bf1;
    bf0.i = *(const int4v*)(W2f + lane * 4);
    bf1.i = *(const int4v*)(W2f + (64 + lane) * 4);
    int c = lane & 15, rg = lane >> 4;

#pragma unroll
    for (int ti = 0; ti < 4; ++ti) {
        int tl = wave * 4 + ti;
        FragU af;
        af.i.x = afrag[tl][0][lane];
        af.i.y = afrag[tl][1][lane];
        af.i.z = afrag[tl][2][lane];
        af.i.w = afrag[tl][3][lane];
        f32x4 a0 = (f32x4){0.f, 0.f, 0.f, 0.f};
        f32x4 a1 = (f32x4){0.f, 0.f, 0.f, 0.f};
        a0 = __builtin_amdgcn_mfma_f32_16x16x32_bf16(af.s, bf0.s, a0, 0, 0, 0);
        a1 = __builtin_amdgcn_mfma_f32_16x16x32_bf16(af.s, bf1.s, a1, 0, 0, 0);
#pragma unroll
        for (int jj = 0; jj < 4; ++jj) {
            int le = tl * 16 + rg * 4 + jj;
            // lane c holds channels (2c, 2c+1) -> one pk atomic, rows fully covered
            atomic_pk_bf16(agg1b + (size_t)dst_lds[le] * C1 + 2 * c,
                           pk_bf16(a0[jj], a1[jj]));
        }
    }
}

// ---------------- finish conv1 (root+bias+elu) and pool1 (pairwise max) + pos mean
__global__ __launch_bounds__(256) void pool1_kernel(
    const unsigned short* __restrict__ agg1b, const float* __restrict__ x,
    const float* __restrict__ root1, const float* __restrict__ bias1,
    const float* __restrict__ pos, unsigned short* __restrict__ x1b,
    float* __restrict__ pos1)
{
    int t = blockIdx.x * blockDim.x + threadIdx.x;
    if (t >= N1P * C1) return;
    int j = t >> 5, o = t & 31;
    int na = 2 * j, nb = 2 * j + 1;
    float r = root1[o], bo = bias1[o];
    float ha = elu1(bf2f(agg1b[(size_t)na * C1 + o]) + x[na] * r + bo);
    float hb = elu1(bf2f(agg1b[(size_t)nb * C1 + o]) + x[nb] * r + bo);
    float mx = fmaxf(ha, hb);
    x1b[t] = (unsigned short)(pk_bf16(mx, mx) & 0xffffu);
    if (o < 2) pos1[j * 2 + o] = 0.5f * (pos[na * 2 + o] + pos[nb * 2 + o]);
}

// ---------------- global max|cart| over pooled edges
__global__ __launch_bounds__(256) void maxabs_kernel(
    const int* __restrict__ ei2, const float* __restrict__ pos1,
    unsigned int* __restrict__ maxbits)
{
    int e = blockIdx.x * blockDim.x + threadIdx.x;
    float m = 0.f;
    if (e < E2P) {
        int s = ei2[e], d = ei2[E2P + e];
        float c0 = pos1[2 * s] - pos1[2 * d];
        float c1 = pos1[2 * s + 1] - pos1[2 * d + 1];
        m = fmaxf(fabsf(c0), fabsf(c1));
    }
#pragma unroll
    for (int off = 32; off; off >>= 1)
        m = fmaxf(m, __shfl_down(m, off));
    if ((threadIdx.x & 63) == 0)
        atomicMax(maxbits, __float_as_uint(m));
}

// ---------------- build conv2 B [832][64] fragments; column perm for pk epilogue:
// MFMA nb, col c -> channel (nb>>1)*32 + 2c + (nb&1)
__global__ __launch_bounds__(256) void bgbuild_kernel(
    const float* __restrict__ w2, const float* __restrict__ b2,
    unsigned int* __restrict__ Bg)
{
    int idx = blockIdx.x * 256 + threadIdx.x;           // pair index, 26624 total
    if (idx >= 26 * 4 * 64 * 4) return;
    int g0 = idx * 2;
    int j = g0 & 7;
    int l = (g0 >> 3) & 63;
    int nb = (g0 >> 9) & 3;
    int kt = g0 >> 11;
    int k = kt * 32 + (l >> 4) * 8 + j;
    int o = (nb >> 1) * 32 + 2 * (l & 15) + (nb & 1);   // perm
    float v0, v1;
    if (k < 800) { v0 = w2[k * 64 + o]; v1 = w2[(k + 1) * 64 + o]; }
    else         { v0 = b2[(k - 800) * 64 + o]; v1 = b2[(k - 799) * 64 + o]; }
    Bg[idx] = pk_bf16(v0, v1);
}

// ---------------- conv2 via MFMA: 256 edges/block, kt-outer, pk-bf16 atomic epilogue
__global__ __launch_bounds__(256) void conv2_kernel(
    const int* __restrict__ ei2, const float* __restrict__ pos1,
    const unsigned short* __restrict__ x1b,
    const float* __restrict__ w1, const float* __restrict__ b1,
    const unsigned int* __restrict__ maxbits,
    const unsigned int* __restrict__ Bg,
    unsigned short* __restrict__ agg2b)
{
    __shared__ __align__(16) unsigned short xs_lds[256][40];  // 20 KB
    __shared__ float hid_lds[256][27];                         // 27.6 KB
    __shared__ int dst_lds[256];

    int t = threadIdx.x;
    int ge = blockIdx.x * 256 + t;

    {   // phase 1: per-edge hid + xs staging (x1 already bf16)
        float inv = 0.5f / __uint_as_float(maxbits[0]);
        int s = 0, d = 0;
        if (ge < E2P) { s = ei2[ge]; d = ei2[E2P + ge]; }
        dst_lds[t] = d;
        float a0 = (pos1[2 * s] - pos1[2 * d]) * inv + 0.5f;
        float a1 = (pos1[2 * s + 1] - pos1[2 * d + 1]) * inv + 0.5f;
#pragma unroll
        for (int h = 0; h < HIDN; ++h) {
            float u = fmaf(a0, w1[h], fmaf(a1, w1[HIDN + h], b1[h]));
            hid_lds[t][h] = fmaxf(u, 0.f);
        }
        const int4v* xp = (const int4v*)(x1b + (size_t)s * C1);
#pragma unroll
        for (int q = 0; q < 4; ++q)
            *(int4v*)&xs_lds[t][q * 8] = xp[q];
    }
    __syncthreads();

    int lane = t & 63, wave = t >> 6;
    int c = lane & 15, rg = lane >> 4;

    FragU xv4[4];
    float xfl[4][8];
#pragma unroll
    for (int ti = 0; ti < 4; ++ti) {
        int row = (wave * 4 + ti) * 16 + c;
        xv4[ti].i = *(const int4v*)&xs_lds[row][rg * 8];
#pragma unroll
        for (int g2 = 0; g2 < 4; ++g2) {
            unsigned int u = (unsigned int)xv4[ti].i[g2];
            xfl[ti][2 * g2]     = __uint_as_float(u << 16);
            xfl[ti][2 * g2 + 1] = __uint_as_float(u & 0xffff0000u);
        }
    }

    f32x4 acc[4][4];
#pragma unroll
    for (int ti = 0; ti < 4; ++ti)
#pragma unroll
        for (int nb = 0; nb < 4; ++nb)
            acc[ti][nb] = (f32x4){0.f, 0.f, 0.f, 0.f};

    const int4v* Bg4 = (const int4v*)Bg;
#pragma unroll 2
    for (int kt = 0; kt < 25; ++kt) {
        FragU bf[4];
#pragma unroll
        for (int nb = 0; nb < 4; ++nb)
            bf[nb].i = Bg4[(kt * 4 + nb) * 64 + lane];
#pragma unroll
        for (int ti = 0; ti < 4; ++ti) {
            float hv = hid_lds[(wave * 4 + ti) * 16 + c][kt];
            FragU af;
            af.i.x = pk_bf16(hv * xfl[ti][0], hv * xfl[ti][1]);
            af.i.y = pk_bf16(hv * xfl[ti][2], hv * xfl[ti][3]);
            af.i.z = pk_bf16(hv * xfl[ti][4], hv * xfl[ti][5]);
            af.i.w = pk_bf16(hv * xfl[ti][6], hv * xfl[ti][7]);
#pragma unroll
            for (int nb = 0; nb < 4; ++nb)
                acc[ti][nb] = __builtin_amdgcn_mfma_f32_16x16x32_bf16(af.s, bf[nb].s, acc[ti][nb], 0, 0, 0);
        }
    }
    {   // kt = 25: b2 term, A = xs directly
        FragU bf[4];
#pragma unroll
        for (int nb = 0; nb < 4; ++nb)
            bf[nb].i = Bg4[(25 * 4 + nb) * 64 + lane];
#pragma unroll
        for (int ti = 0; ti < 4; ++ti)
#pragma unroll
            for (int nb = 0; nb < 4; ++nb)
                acc[ti][nb] = __builtin_amdgcn_mfma_f32_16x16x32_bf16(xv4[ti].s, bf[nb].s, acc[ti][nb], 0, 0, 0);
    }

    // epilogue: lane c holds channels (2c,2c+1) [nb 0,1] and (32+2c,32+2c+1) [nb 2,3]
#pragma unroll
    for (int ti = 0; ti < 4; ++ti) {
        int tl = wave * 4 + ti;
#pragma unroll
        for (int jj = 0; jj < 4; ++jj) {
            int le = tl * 16 + rg * 4 + jj;
            if (blockIdx.x * 256 + le < E2P) {
                unsigned short* dp = agg2b + (size_t)dst_lds[le] * C2;
                atomic_pk_bf16(dp + 2 * c,      pk_bf16(acc[ti][0][jj], acc[ti][1][jj]));
                atomic_pk_bf16(dp + 32 + 2 * c, pk_bf16(acc[ti][2][jj], acc[ti][3][jj]));
            }
        }
    }
}

// ---------------- finish conv2 (root2+bias2+elu), pool2 (pairwise max), per-graph mean
__global__ __launch_bounds__(256) void pool2_kernel(
    const unsigned short* __restrict__ agg2b, const unsigned short* __restrict__ x1b,
    const float* __restrict__ root2, const float* __restrict__ bias2,
    float* __restrict__ g)
{
    int b = blockIdx.x;
    int w = threadIdx.x >> 6, o = threadIdx.x & 63;
    __shared__ float part[4][C2];
    float sum = 0.f;
    for (int jj = w; jj < 50; jj += 4) {
        int j = b * 50 + jj;
        float hv[2];
#pragma unroll
        for (int t = 0; t < 2; ++t) {
            int n = 2 * j + t;
            float a = bf2f(agg2b[(size_t)n * C2 + o]) + bias2[o];
#pragma unroll
            for (int i = 0; i < C1; ++i)
                a = fmaf(bf2f(x1b[(size_t)n * C1 + i]), root2[i * C2 + o], a);
            hv[t] = elu1(a);
        }
        sum += fmaxf(hv[0], hv[1]);
    }
    part[w][o] = sum;
    __syncthreads();
    if (w == 0) {
        float s2 = part[0][o] + part[1][o] + part[2][o] + part[3][o];
        g[b * C2 + o] = s2 * (1.f / 50.f);
    }
}

// ---------------- FC head
__global__ __launch_bounds__(128) void head_kernel(
    const float* __restrict__ g,
    const float* __restrict__ fc1w, const float* __restrict__ fc1b,
    const float* __restrict__ fc2w, const float* __restrict__ fc2b,
    float* __restrict__ out)
{
    int b = blockIdx.x;
    int t = threadIdx.x;
    __shared__ float gs[C2];
    __shared__ float zs[128];
    __shared__ float ls[NCLS];
    if (t < C2) gs[t] = g[b * C2 + t];
    __syncthreads();
    float z = fc1b[t];
#pragma unroll
    for (int i = 0; i < C2; ++i) z = fmaf(gs[i], fc1w[i * 128 + t], z);
    zs[t] = elu1(z);
    __syncthreads();
    if (t < NCLS) {
        float l = fc2b[t];
#pragma unroll
        for (int k = 0; k < 128; ++k) l = fmaf(zs[k], fc2w[k * NCLS + t], l);
        ls[t] = l;
    }
    __syncthreads();
    if (t < NCLS) {
        float mx = ls[0];
#pragma unroll
        for (int c = 1; c < NCLS; ++c) mx = fmaxf(mx, ls[c]);
        float se = 0.f;
#pragma unroll
        for (int c = 0; c < NCLS; ++c) se += expf(ls[c] - mx);
        out[b * NCLS + t] = ls[t] - mx - logf(se);
    }
}

extern "C" void kernel_launch(void* const* d_in, const int* in_sizes, int n_in,
                              void* d_out, int out_size, void* d_ws, size_t ws_size,
                              hipStream_t stream)
{
    const float* x    = (const float*)d_in[0];
    const float* pos  = (const float*)d_in[1];
    const int*   ei   = (const int*)d_in[2];
    const float* ea   = (const float*)d_in[3];
    const int*   ei2  = (const int*)d_in[6];
    const float* n1w1 = (const float*)d_in[8];
    const float* n1b1 = (const float*)d_in[9];
    const float* n1w2 = (const float*)d_in[10];
    const float* n1b2 = (const float*)d_in[11];
    const float* root1= (const float*)d_in[12];
    const float* bias1= (const float*)d_in[13];
    const float* n2w1 = (const float*)d_in[14];
    const float* n2b1 = (const float*)d_in[15];
    const float* n2w2 = (const float*)d_in[16];
    const float* n2b2 = (const float*)d_in[17];
    const float* root2= (const float*)d_in[18];
    const float* bias2= (const float*)d_in[19];
    const float* fc1w = (const float*)d_in[20];
    const float* fc1b = (const float*)d_in[21];
    const float* fc2w = (const float*)d_in[22];
    const float* fc2b = (const float*)d_in[23];
    float* out = (float*)d_out;

    char* w = (char*)d_ws;
    unsigned short* agg1b = (unsigned short*)w;  w += (size_t)N_NODES * C1 * 2;   // 12.8 MB
    unsigned short* x1b   = (unsigned short*)w;  w += (size_t)N1P * C1 * 2;       // 6.4 MB
    float* pos1 = (float*)w;                     w += (size_t)N1P * 2 * 4;        // 0.8 MB
    unsigned int* maxbits = (unsigned int*)w;    w += 256;
    unsigned short* agg2b = (unsigned short*)w;  w += (size_t)N1P * C2 * 2;       // 12.8 MB
    float* g    = (float*)w;                     w += (size_t)BGR * C2 * 4;
    unsigned int* Bg = (unsigned int*)w;         w += 26624 * 4;
    unsigned int* W2f = (unsigned int*)w;        w += 512 * 4;

    hipMemsetAsync(agg1b, 0, (size_t)N_NODES * C1 * 2, stream);
    hipMemsetAsync(agg2b, 0, (size_t)N1P * C2 * 2, stream);
    hipMemsetAsync(maxbits, 0, 256, stream);

    bgbuild1_kernel<<<2, 256, 0, stream>>>(n1w2, n1b2, W2f);
    bgbuild_kernel<<<104, 256, 0, stream>>>(n2w2, n2b2, Bg);
    conv1_kernel<<<E1 / 256, 256, 0, stream>>>(x, ea, ei, n1w1, n1b1, W2f, agg1b);
    pool1_kernel<<<(N1P * C1 + 255) / 256, 256, 0, stream>>>(agg1b, x, root1, bias1, pos, x1b, pos1);
    maxabs_kernel<<<(E2P + 255) / 256, 256, 0, stream>>>(ei2, pos1, maxbits);
    conv2_kernel<<<(E2P + 255) / 256, 256, 0, stream>>>(ei2, pos1, x1b, n2w1, n2b1, maxbits, Bg, agg2b);
    pool2_kernel<<<BGR, 256, 0, stream>>>(agg2b, x1b, root2, bias2, g);
    head_kernel<<<BGR, 128, 0, stream>>>(g, fc1w, fc1b, fc2w, fc2b, out);
}